// Round 12
// baseline (3047.290 us; speedup 1.0000x reference)
//
#include <hip/hip_runtime.h>

// AttentionRNN: B=1024, T=256, U=256.
//  Xh = fp16(X); P[t] = x_t @ [Wemb|Wre|Wnew] (fp16 MFMA GEMM, CT chunks).
//  Recurrent v4 (dual-group half-step pipeline): 128 blocks x 8 rows x 8 waves.
//  Rows split G0=0..3 / G1=4..7, advanced on alternating half-steps:
//  each half = {phase2 of active group} || {MFMA qg-pass for the OTHER group}.
//  MFMA C-row r depends only on A-row r, so the pass validly computes the
//  inactive group's qg while the active group's stA rows are rewritten.
//  One lgkm-only barrier per half. Weights persistent: kt0..5 in 192 VGPRs
//  (keep-alive pinned), kt6..7 in 128 KB LDS. av[8] batched (8 back-to-back
//  ds_reads instead of 32 serialized read->MFMA chains).

typedef _Float16 f16;
typedef _Float16 f16x8 __attribute__((ext_vector_type(8)));
typedef _Float16 f16x4 __attribute__((ext_vector_type(4)));
typedef float f32x4 __attribute__((ext_vector_type(4)));

static __device__ __forceinline__ f32x4 mfma16(f16x8 a, f16x8 b, f32x4 c){
  return __builtin_amdgcn_mfma_f32_16x16x32_f16(a, b, c, 0, 0, 0);
}
static __device__ __forceinline__ float sigmoid_f(float x){
  return 1.0f / (1.0f + __expf(-x));
}
static __device__ __forceinline__ float tanh_f(float x){
  float e = __expf(2.0f * x);
  return 1.0f - 2.0f / (e + 1.0f);   // stable
}
static __device__ __forceinline__ void lgkm_barrier(){
  asm volatile("s_waitcnt lgkmcnt(0)" ::: "memory");
  __builtin_amdgcn_s_barrier();
}

// ---------------- cast X fp32 -> fp16 (same layout) ----------------
__global__ void cast_x_kernel(const float* __restrict__ X, f16* __restrict__ Xh){
  size_t e = ((size_t)blockIdx.x * 256 + threadIdx.x) * 8;
  f32x4 v0 = *(const f32x4*)(X + e);
  f32x4 v1 = *(const f32x4*)(X + e + 4);
  f16x8 h;
  #pragma unroll
  for (int j = 0; j < 8; ++j) h[j] = (f16)((j < 4) ? v0[j] : v1[j-4]);
  *(f16x8*)(Xh + e) = h;
}

// ------------- cast weights to fp16 -------------
__global__ void cast_w_kernel(const float* __restrict__ EK, const float* __restrict__ RE,
    const float* __restrict__ NW, const float* __restrict__ SK, const float* __restrict__ RS,
    f16* __restrict__ WcatT, f16* __restrict__ WsrF){
  int tid = blockIdx.x * 256 + threadIdx.x;
  if (tid < 458752){
    int n = tid >> 8, k = tid & 255;
    float v;
    if (n < 256)       v = EK[k*256 + n];
    else if (n < 1024) v = RE[k*768 + (n-256)];
    else               v = NW[k*768 + (n-1024)];
    WcatT[n*256 + k] = (f16)v;
  } else {
    int idx = tid - 458752;            // 0..262143
    int e    = idx & 7;
    int lane = (idx >> 3) & 63;
    int kt   = (idx >> 9) & 7;
    int ct   = idx >> 12;              // 0..63
    int col  = ct*16 + (lane & 15);
    int k    = kt*32 + ((lane >> 4) & 3)*8 + e;
    float v = (col < 256) ? SK[k*256 + col] : RS[k*768 + (col-256)];
    WsrF[idx] = (f16)v;
  }
}

// ---- GEMM: C[r=tsl*1024+b][0:1792) = Xh[b][t_start+tsl][:] @ WcatT^T ----
__global__ __launch_bounds__(256, 2) void gemm_f16_kernel(
    const f16* __restrict__ Xh, const f16* __restrict__ Bm,
    f16* __restrict__ C, int Mtiles, int t_start)
{
  __shared__ f16 As[128*64];
  __shared__ f16 Bs[128*64];
  const int NT = 14;
  const int nwg = Mtiles * NT;
  int bid = blockIdx.x, wg = bid;
  if ((nwg & 7) == 0){ int cpx = nwg >> 3; wg = (bid & 7) * cpx + (bid >> 3); }
  const int mt = wg / NT, nt = wg % NT;
  const int tsl = mt >> 3;
  const int b0  = (mt & 7) * 128;
  const int t   = t_start + tsl;
  const int n0  = nt * 128;
  const int tid = threadIdx.x;
  const int l = tid & 63, wid = tid >> 6;
  const int wr = wid >> 1, wc = wid & 1;
  const int srow = tid >> 3;
  const int scol = (tid & 7) * 8;

  const size_t ASTR = 32ull * 65536ull;
  const f16* Ab = Xh + ((size_t)(b0 + srow) * 256 + t) * 256 + scol;
  const f16* Bb = Bm + ((size_t)(n0 + srow)) * 256 + scol;

  f16x8 ra[4], rb[4];
  #pragma unroll
  for (int j = 0; j < 4; ++j){
    ra[j] = *(const f16x8*)(Ab + (size_t)j * ASTR);
    rb[j] = *(const f16x8*)(Bb + (size_t)j * 32 * 256);
  }

  f32x4 acc[4][4];
  #pragma unroll
  for (int mi = 0; mi < 4; ++mi)
    #pragma unroll
    for (int ni = 0; ni < 4; ++ni)
      acc[mi][ni] = (f32x4){0.f,0.f,0.f,0.f};

  for (int kt = 0; kt < 4; ++kt){
    #pragma unroll
    for (int j = 0; j < 4; ++j){
      int row = srow + j*32;
      int e = (row*64 + scol) ^ ((row & 7) << 3);
      *(f16x8*)&As[e] = ra[j];
      *(f16x8*)&Bs[e] = rb[j];
    }
    __syncthreads();
    if (kt < 3){
      #pragma unroll
      for (int j = 0; j < 4; ++j){
        ra[j] = *(const f16x8*)(Ab + (kt+1)*64 + (size_t)j * ASTR);
        rb[j] = *(const f16x8*)(Bb + (kt+1)*64 + (size_t)j * 32 * 256);
      }
    }
    #pragma unroll
    for (int kk = 0; kk < 2; ++kk){
      f16x8 af[4], bfr[4];
      #pragma unroll
      for (int mi = 0; mi < 4; ++mi){
        int row = wr*64 + mi*16 + (l & 15);
        int e = (row*64 + kk*32 + (l >> 4)*8) ^ ((row & 7) << 3);
        af[mi] = *(const f16x8*)&As[e];
      }
      #pragma unroll
      for (int ni = 0; ni < 4; ++ni){
        int row = wc*64 + ni*16 + (l & 15);
        int e = (row*64 + kk*32 + (l >> 4)*8) ^ ((row & 7) << 3);
        bfr[ni] = *(const f16x8*)&Bs[e];
      }
      #pragma unroll
      for (int mi = 0; mi < 4; ++mi)
        #pragma unroll
        for (int ni = 0; ni < 4; ++ni)
          acc[mi][ni] = mfma16(af[mi], bfr[ni], acc[mi][ni]);
    }
    __syncthreads();
  }
  const size_t m0 = (size_t)mt * 128;
  #pragma unroll
  for (int mi = 0; mi < 4; ++mi){
    #pragma unroll
    for (int ni = 0; ni < 4; ++ni){
      int col = n0 + wc*64 + ni*16 + (l & 15);
      size_t row = m0 + wr*64 + mi*16 + ((l >> 4) * 4);
      #pragma unroll
      for (int j = 0; j < 4; ++j)
        C[(row + j) * 1792 + col] = (f16)acc[mi][ni][j];
    }
  }
}

// ---- qg pass for group GP: 64 MFMAs, av[8] batched, writes qgdb[GP] ----
template<int GP>
static __device__ __forceinline__ void qg_pass(
    f16x8 (&Wreg)[8][6], const f16* __restrict__ Wl_w,
    const f16* __restrict__ stA_l, f16* __restrict__ qgdb, int w, int l)
{
  const int agrp = l >> 4, arow = l & 15;
  f16x8 av[8];
  #pragma unroll
  for (int kt = 0; kt < 8; ++kt) av[kt] = *(const f16x8*)(stA_l + kt*520);
  #pragma unroll
  for (int qtr = 0; qtr < 4; ++qtr){
    const int c0 = qtr*2, c1 = qtr*2 + 1;
    f32x4 a0 = (f32x4){0.f,0.f,0.f,0.f}, a1 = a0;
    #pragma unroll
    for (int kt = 0; kt < 8; ++kt){
      f16x8 B0 = (kt < 6) ? Wreg[c0][kt]
                          : *(const f16x8*)(Wl_w + (c0*2 + (kt-6))*512 + l*8);
      f16x8 B1 = (kt < 6) ? Wreg[c1][kt]
                          : *(const f16x8*)(Wl_w + (c1*2 + (kt-6))*512 + l*8);
      a0 = mfma16(av[kt], B0, a0);
      a1 = mfma16(av[kt], B1, a1);
    }
    if (agrp == GP){
      #pragma unroll
      for (int j = 0; j < 4; ++j){
        qgdb[GP*4128 + j*1032 + w*128 + c0*16 + arow] = (f16)a0[j];
        qgdb[GP*4128 + j*1032 + w*128 + c1*16 + arow] = (f16)a1[j];
      }
    }
  }
}

// ---- one half-step: phase2(G, step i) || qg-pass(1-G) ----
template<int G>
static __device__ __forceinline__ void half_body(
    int i, int t_abs, const f16* __restrict__ P, int r0, int tid,
    f16x8 (&Wreg)[8][6], const f16* __restrict__ Wl, f16* __restrict__ qgdb,
    f16* __restrict__ stA, const float* __restrict__ sb, const float* __restrict__ sl,
    f32x4& sn, f16* sa, float* __restrict__ out)
{
  constexpr int GP = 1 - G;
  const int l = tid & 63, w = tid >> 6;
  const int c4 = l * 4;
  const size_t SL = 1024ull*1792ull;
  const f16* stA_l = stA + l*8;
  const f16* Wl_w  = Wl + w*8192;

  // early P loads (group G, step i): 9 vectors, covered by the pass below
  f16x4 E0, E1, E2, Uc, Rc, Cc, NU, NR, NC;
  const f16 *p2 = P, *p1 = P, *p0 = P;
  if (w < 4){
    const size_t gbo = (size_t)(r0 + G*4 + w)*1792;
    p2 = P + (size_t)(i+2)*SL + gbo;
    p1 = P + (size_t)(i+1)*SL + gbo;
    p0 = P + (size_t)(i+0)*SL + gbo;
    E2 = *(const f16x4*)(p2 + c4);
    E1 = *(const f16x4*)(p1 + c4);
    E0 = *(const f16x4*)(p0 + c4);
    Uc = *(const f16x4*)(p2 +  256 + c4);
    Rc = *(const f16x4*)(p2 +  512 + c4);
    Cc = *(const f16x4*)(p2 +  768 + c4);
    NU = *(const f16x4*)(p2 + 1024 + c4);
    NR = *(const f16x4*)(p2 + 1280 + c4);
    NC = *(const f16x4*)(p2 + 1536 + c4);
  }

  // keep-alive: pin persistent weights across the loop
  #pragma unroll
  for (int ct = 0; ct < 8; ++ct)
    #pragma unroll
    for (int kt = 0; kt < 6; ++kt)
      asm volatile("" : "+v"(Wreg[ct][kt]));

  // MFMA pass for the inactive group (reads its stable stA rows)
  qg_pass<GP>(Wreg, Wl_w, stA_l, qgdb, w, l);

  // phase2 for active group G (row w of the group), waves 0-3 only
  if (w < 4){
    // warm loads (slabs i, i+1: L2-resident)
    const f16x4 U1 = *(const f16x4*)(p1 + 256 + c4);
    const f16x4 R1 = *(const f16x4*)(p1 + 512 + c4);
    const f16x4 C1 = *(const f16x4*)(p1 + 768 + c4);
    const f16x4 U2 = *(const f16x4*)(p0 + 256 + c4);
    const f16x4 R2 = *(const f16x4*)(p0 + 512 + c4);
    const f16x4 C2 = *(const f16x4*)(p0 + 768 + c4);

    const f16* qrow = qgdb + G*4128 + w*1032;
    const f16x4 qv = *(const f16x4*)(qrow + c4);
    const f16x4 qu = *(const f16x4*)(qrow + 256 + c4);
    const f16x4 qr = *(const f16x4*)(qrow + 512 + c4);
    const f16x4 qc = *(const f16x4*)(qrow + 768 + c4);
    const f32x4 bb = *(const f32x4*)(sb + c4);
    const f32x4 lk = *(const f32x4*)(sl + c4);

    float s0 = 0.f, s1 = 0.f, s2 = 0.f;
    #pragma unroll
    for (int j = 0; j < 4; ++j){
      const float qb = (float)qv[j] + bb[j];
      s0 += tanh_f((float)E0[j] + qb) * lk[j];
      s1 += tanh_f((float)E1[j] + qb) * lk[j];
      s2 += tanh_f((float)E2[j] + qb) * lk[j];
    }
    #pragma unroll
    for (int off = 32; off; off >>= 1){
      s0 += __shfl_xor(s0, off);
      s1 += __shfl_xor(s1, off);
      s2 += __shfl_xor(s2, off);
    }
    const float mx = fmaxf(fmaxf(s0, s1), s2);
    const float x0 = __expf(s0 - mx), x1 = __expf(s1 - mx), x2 = __expf(s2 - mx);
    const float inv = 1.0f / (x0 + x1 + x2);
    const float pr0 = x0*inv, pr1 = x1*inv, pr2 = x2*inv;

    #pragma unroll
    for (int j = 0; j < 4; ++j){
      const float geu = pr2*(float)Uc[j] + pr1*(float)U1[j] + pr0*(float)U2[j];
      const float ger = pr2*(float)Rc[j] + pr1*(float)R1[j] + pr0*(float)R2[j];
      const float gec = pr2*(float)Cc[j] + pr1*(float)C1[j] + pr0*(float)C2[j];
      const float up   = sigmoid_f((float)qu[j] + geu + (float)NU[j]);
      const float rp   = sigmoid_f((float)qr[j] + ger + (float)NR[j]);
      const float cand = tanh_f(rp*(float)qc[j] + gec + (float)NC[j]);
      sn[j] = (1.0f - up)*sn[j] + up*cand;
    }
    { f16x4 h; h[0]=(f16)sn[0]; h[1]=(f16)sn[1]; h[2]=(f16)sn[2]; h[3]=(f16)sn[3]; *(f16x4*)sa = h; }
    if (t_abs == 255){
      *(f32x4*)(out + (size_t)(r0 + G*4 + w)*256 + c4) = sn;
    }
  }
  lgkm_barrier();
}

// ---------- recurrent v4: 128 blocks x 8 rows, 512 threads (8 waves) ----------
__global__ __launch_bounds__(512, 1) void recurrent_kernel(
    const f16* __restrict__ P, const f16* __restrict__ WsrF,
    const float* __restrict__ bias, const float* __restrict__ Lk,
    float* __restrict__ state, float* __restrict__ out,
    int t0, int nsteps)
{
  __shared__ f16 Wl[8*8192];       // weights kt6..7: 128 KB
  __shared__ f16 qgdb[2*4*1032];   // per-group qg (G0 | G1), f16
  __shared__ f16 stA[8*520];       // state f16, fragment-major [kt][lane][8]
  __shared__ __align__(16) float sb[256];
  __shared__ __align__(16) float sl[256];

  const int tid = threadIdx.x;
  const int l = tid & 63, w = tid >> 6;
  const int r0 = blockIdx.x * 8;
  const int c4 = l * 4;

  if (tid < 256){ sb[tid] = bias[tid]; sl[tid] = Lk[tid]; }
  for (int j = tid; j < 8*520; j += 512) stA[j] = (f16)0.f;

  // persistent weights: kt0..5 -> 192 VGPRs/wave
  const f16* const wbase = WsrF + (size_t)w*32768 + l*8;
  f16x8 Wreg[8][6];
  #pragma unroll
  for (int ct = 0; ct < 8; ++ct)
    #pragma unroll
    for (int kt = 0; kt < 6; ++kt)
      Wreg[ct][kt] = *(const f16x8*)(wbase + (ct*8 + kt)*512);
  // kt6..7 -> LDS
  #pragma unroll
  for (int ct = 0; ct < 8; ++ct)
    #pragma unroll
    for (int k2 = 0; k2 < 2; ++k2)
      *(f16x8*)&Wl[w*8192 + (ct*2 + k2)*512 + l*8] =
          *(const f16x8*)(wbase + (ct*8 + 6 + k2)*512);
  __syncthreads();

  // state: wave w<4 owns G0 row w and G1 row w+4
  f32x4 snA = (f32x4){0.f,0.f,0.f,0.f}, snB = snA;
  f16 *saA = stA, *saB = stA;
  if (w < 4){
    snA = *(const f32x4*)(state + (size_t)(r0 + w)*256 + c4);
    snB = *(const f32x4*)(state + (size_t)(r0 + 4 + w)*256 + c4);
    saA = &stA[(l >> 3)*520 + ((((l >> 1) & 3) << 4) + w)*8 + (l & 1)*4];
    saB = &stA[(l >> 3)*520 + ((((l >> 1) & 3) << 4) + w + 4)*8 + (l & 1)*4];
    { f16x4 h; h[0]=(f16)snA[0]; h[1]=(f16)snA[1]; h[2]=(f16)snA[2]; h[3]=(f16)snA[3]; *(f16x4*)saA = h; }
    { f16x4 h; h[0]=(f16)snB[0]; h[1]=(f16)snB[1]; h[2]=(f16)snB[2]; h[3]=(f16)snB[3]; *(f16x4*)saB = h; }
  }
  lgkm_barrier();

  // prologue pass: qg for G0 at its initial state
  qg_pass<0>(Wreg, Wl + w*8192, stA + l*8, qgdb, w, l);
  lgkm_barrier();

  for (int i = 0; i < nsteps; ++i){
    const int t_abs = t0 + i;
    half_body<0>(i, t_abs, P, r0, tid, Wreg, Wl, qgdb, stA, sb, sl, snA, saA, out);
    half_body<1>(i, t_abs, P, r0, tid, Wreg, Wl, qgdb, stA, sb, sl, snB, saB, out);
  }

  if (w < 4){
    *(f32x4*)(state + (size_t)(r0 + w)*256 + c4)     = snA;
    *(f32x4*)(state + (size_t)(r0 + 4 + w)*256 + c4) = snB;
  }
}

// ---------------------------------- launch ----------------------------------
extern "C" void kernel_launch(void* const* d_in, const int* in_sizes, int n_in,
                              void* d_out, int out_size, void* d_ws, size_t ws_size,
                              hipStream_t stream)
{
  const float* X  = (const float*)d_in[0];
  const float* EK = (const float*)d_in[1];
  const float* SK = (const float*)d_in[2];
  const float* BI = (const float*)d_in[3];
  const float* LK = (const float*)d_in[4];
  const float* RS = (const float*)d_in[5];
  const float* RE = (const float*)d_in[6];
  const float* NW = (const float*)d_in[7];
  float* out = (float*)d_out;
  char* ws = (char*)d_ws;

  const size_t slabB = 1024ull * 1792ull * 2ull;   // 3,670,016 B
  const size_t XhB   = 134217728ull;               // 1024*256*256 f16
  const size_t wB    = 917504ull + 524288ull + 1048576ull;
  int CT = 4;
  if      (ws_size >= 34ull*slabB + XhB + wB) CT = 32;
  else if (ws_size >= 18ull*slabB + XhB + wB) CT = 16;
  else if (ws_size >= 10ull*slabB + XhB + wB) CT = 8;

  f16* P = (f16*)ws;
  size_t poff = (size_t)(CT + 2) * slabB;
  f16* Xh    = (f16*)(ws + poff);
  f16* WcatT = (f16*)(ws + poff + XhB);
  f16* WsrF  = (f16*)(ws + poff + XhB + 917504ull);
  float* state = (float*)(ws + poff + XhB + 917504ull + 524288ull);

  hipMemsetAsync(state, 0, 1048576ull, stream);
  hipMemsetAsync(P, 0, 2ull*slabB, stream);        // zero "virtual" slabs t=-2,-1
  cast_x_kernel<<<32768, 256, 0, stream>>>(X, Xh);
  cast_w_kernel<<<2816, 256, 0, stream>>>(EK, RE, NW, SK, RS, WcatT, WsrF);

  const int nch = 256 / CT;
  for (int c = 0; c < nch; ++c){
    const int t0 = c * CT;
    const int t_start  = (c == 0) ? 0 : (t0 - 2);
    const int slab_off = (c == 0) ? 2 : 0;
    const int Mtiles = (((c == 0) ? CT : (CT + 2)) * 1024) / 128;
    gemm_f16_kernel<<<Mtiles * 14, 256, 0, stream>>>(
        Xh, WcatT, P + (size_t)slab_off * 1024 * 1792, Mtiles, t_start);
    recurrent_kernel<<<128, 512, 0, stream>>>(P, WsrF, BI, LK, state, out, t0, CT);
  }
}

// Round 13
// 2440.901 us; speedup vs baseline: 1.2484x; 1.2484x over previous
//
#include <hip/hip_runtime.h>

// AttentionRNN: B=1024, T=256, U=256.
//  Xh = fp16(X); P[t] = x_t @ [Wemb|Wre|Wnew] (fp16 MFMA GEMM, CT chunks).
//  Recurrent v5 (= r11 + batched av + reg bias/Lk + upfront P loads):
//  128 blocks x 8 rows x 8 waves. Weights persistent: kt0..5 in 192 regs/wave
//  (keep-alive pinned), kt6..7 in 128 KB LDS. av[8] batched once per step
//  (was 32 serialized ds_read->MFMA chains = ~4K cyc/step). All 15 P vectors
//  issued at step start (pass has no vmem -> nothing gates on them until
//  phase 2, fully latency-hidden). lgkm-only barriers.

typedef _Float16 f16;
typedef _Float16 f16x8 __attribute__((ext_vector_type(8)));
typedef _Float16 f16x4 __attribute__((ext_vector_type(4)));
typedef float f32x4 __attribute__((ext_vector_type(4)));

static __device__ __forceinline__ f32x4 mfma16(f16x8 a, f16x8 b, f32x4 c){
  return __builtin_amdgcn_mfma_f32_16x16x32_f16(a, b, c, 0, 0, 0);
}
static __device__ __forceinline__ float sigmoid_f(float x){
  return 1.0f / (1.0f + __expf(-x));
}
static __device__ __forceinline__ float tanh_f(float x){
  float e = __expf(2.0f * x);
  return 1.0f - 2.0f / (e + 1.0f);   // stable
}
static __device__ __forceinline__ void lgkm_barrier(){
  asm volatile("s_waitcnt lgkmcnt(0)" ::: "memory");
  __builtin_amdgcn_s_barrier();
}

// ---------------- cast X fp32 -> fp16 (same layout) ----------------
__global__ void cast_x_kernel(const float* __restrict__ X, f16* __restrict__ Xh){
  size_t e = ((size_t)blockIdx.x * 256 + threadIdx.x) * 8;
  f32x4 v0 = *(const f32x4*)(X + e);
  f32x4 v1 = *(const f32x4*)(X + e + 4);
  f16x8 h;
  #pragma unroll
  for (int j = 0; j < 8; ++j) h[j] = (f16)((j < 4) ? v0[j] : v1[j-4]);
  *(f16x8*)(Xh + e) = h;
}

// ------------- cast weights to fp16 -------------
__global__ void cast_w_kernel(const float* __restrict__ EK, const float* __restrict__ RE,
    const float* __restrict__ NW, const float* __restrict__ SK, const float* __restrict__ RS,
    f16* __restrict__ WcatT, f16* __restrict__ WsrF){
  int tid = blockIdx.x * 256 + threadIdx.x;
  if (tid < 458752){
    int n = tid >> 8, k = tid & 255;
    float v;
    if (n < 256)       v = EK[k*256 + n];
    else if (n < 1024) v = RE[k*768 + (n-256)];
    else               v = NW[k*768 + (n-1024)];
    WcatT[n*256 + k] = (f16)v;
  } else {
    int idx = tid - 458752;            // 0..262143
    int e    = idx & 7;
    int lane = (idx >> 3) & 63;
    int kt   = (idx >> 9) & 7;
    int ct   = idx >> 12;              // 0..63
    int col  = ct*16 + (lane & 15);
    int k    = kt*32 + ((lane >> 4) & 3)*8 + e;
    float v = (col < 256) ? SK[k*256 + col] : RS[k*768 + (col-256)];
    WsrF[idx] = (f16)v;
  }
}

// ---- GEMM: C[r=tsl*1024+b][0:1792) = Xh[b][t_start+tsl][:] @ WcatT^T ----
__global__ __launch_bounds__(256, 2) void gemm_f16_kernel(
    const f16* __restrict__ Xh, const f16* __restrict__ Bm,
    f16* __restrict__ C, int Mtiles, int t_start)
{
  __shared__ f16 As[128*64];
  __shared__ f16 Bs[128*64];
  const int NT = 14;
  const int nwg = Mtiles * NT;
  int bid = blockIdx.x, wg = bid;
  if ((nwg & 7) == 0){ int cpx = nwg >> 3; wg = (bid & 7) * cpx + (bid >> 3); }
  const int mt = wg / NT, nt = wg % NT;
  const int tsl = mt >> 3;
  const int b0  = (mt & 7) * 128;
  const int t   = t_start + tsl;
  const int n0  = nt * 128;
  const int tid = threadIdx.x;
  const int l = tid & 63, wid = tid >> 6;
  const int wr = wid >> 1, wc = wid & 1;
  const int srow = tid >> 3;
  const int scol = (tid & 7) * 8;

  const size_t ASTR = 32ull * 65536ull;
  const f16* Ab = Xh + ((size_t)(b0 + srow) * 256 + t) * 256 + scol;
  const f16* Bb = Bm + ((size_t)(n0 + srow)) * 256 + scol;

  f16x8 ra[4], rb[4];
  #pragma unroll
  for (int j = 0; j < 4; ++j){
    ra[j] = *(const f16x8*)(Ab + (size_t)j * ASTR);
    rb[j] = *(const f16x8*)(Bb + (size_t)j * 32 * 256);
  }

  f32x4 acc[4][4];
  #pragma unroll
  for (int mi = 0; mi < 4; ++mi)
    #pragma unroll
    for (int ni = 0; ni < 4; ++ni)
      acc[mi][ni] = (f32x4){0.f,0.f,0.f,0.f};

  for (int kt = 0; kt < 4; ++kt){
    #pragma unroll
    for (int j = 0; j < 4; ++j){
      int row = srow + j*32;
      int e = (row*64 + scol) ^ ((row & 7) << 3);
      *(f16x8*)&As[e] = ra[j];
      *(f16x8*)&Bs[e] = rb[j];
    }
    __syncthreads();
    if (kt < 3){
      #pragma unroll
      for (int j = 0; j < 4; ++j){
        ra[j] = *(const f16x8*)(Ab + (kt+1)*64 + (size_t)j * ASTR);
        rb[j] = *(const f16x8*)(Bb + (kt+1)*64 + (size_t)j * 32 * 256);
      }
    }
    #pragma unroll
    for (int kk = 0; kk < 2; ++kk){
      f16x8 af[4], bfr[4];
      #pragma unroll
      for (int mi = 0; mi < 4; ++mi){
        int row = wr*64 + mi*16 + (l & 15);
        int e = (row*64 + kk*32 + (l >> 4)*8) ^ ((row & 7) << 3);
        af[mi] = *(const f16x8*)&As[e];
      }
      #pragma unroll
      for (int ni = 0; ni < 4; ++ni){
        int row = wc*64 + ni*16 + (l & 15);
        int e = (row*64 + kk*32 + (l >> 4)*8) ^ ((row & 7) << 3);
        bfr[ni] = *(const f16x8*)&Bs[e];
      }
      #pragma unroll
      for (int mi = 0; mi < 4; ++mi)
        #pragma unroll
        for (int ni = 0; ni < 4; ++ni)
          acc[mi][ni] = mfma16(af[mi], bfr[ni], acc[mi][ni]);
    }
    __syncthreads();
  }
  const size_t m0 = (size_t)mt * 128;
  #pragma unroll
  for (int mi = 0; mi < 4; ++mi){
    #pragma unroll
    for (int ni = 0; ni < 4; ++ni){
      int col = n0 + wc*64 + ni*16 + (l & 15);
      size_t row = m0 + wr*64 + mi*16 + ((l >> 4) * 4);
      #pragma unroll
      for (int j = 0; j < 4; ++j)
        C[(row + j) * 1792 + col] = (f16)acc[mi][ni][j];
    }
  }
}

// ---------- recurrent v5: 128 blocks x 8 rows, 512 threads (8 waves) ----------
__global__ __launch_bounds__(512, 1) void recurrent_kernel(
    const f16* __restrict__ P, const f16* __restrict__ WsrF,
    const float* __restrict__ bias, const float* __restrict__ Lk,
    float* __restrict__ state, float* __restrict__ out,
    int t0, int nsteps)
{
  __shared__ f16 Wl[8*8192];             // weights kt6..7: 128 KB
  __shared__ f16 qg16[8*1032];           // qg as f16: [row][1032]
  __shared__ f16 stA[8*520];             // state f16, fragment-major [kt][lane][8]

  const int tid = threadIdx.x;
  const int l = tid & 63, w = tid >> 6;  // 8 waves, wave w owns row w
  const int r0 = blockIdx.x * 8;
  const int arow = l & 15, agrp = l >> 4;
  const int c4 = l * 4;
  const int gb = r0 + w;
  const size_t SL = 1024ull*1792ull;
  const size_t gbo = (size_t)gb*1792;

  // per-lane score constants in registers (read-only, loaded once)
  const f32x4 bb = *(const f32x4*)(bias + c4);
  const f32x4 lk = *(const f32x4*)(Lk + c4);

  for (int j = tid; j < 8*520; j += 512) stA[j] = (f16)0.f;

  // ---- persistent weights: kt0..5 -> 192 regs/wave ----
  const f16* const wbase = WsrF + (size_t)w*32768 + l*8;   // wave's 8 ct-tiles
  f16x8 Wreg[8][6];
  #pragma unroll
  for (int ct = 0; ct < 8; ++ct)
    #pragma unroll
    for (int kt = 0; kt < 6; ++kt)
      Wreg[ct][kt] = *(const f16x8*)(wbase + (ct*8 + kt)*512);
  // ---- kt6..7 -> LDS (128 KB, loaded once) ----
  #pragma unroll
  for (int ct = 0; ct < 8; ++ct)
    #pragma unroll
    for (int k2 = 0; k2 < 2; ++k2)
      *(f16x8*)&Wl[w*8192 + (ct*2 + k2)*512 + l*8] =
          *(const f16x8*)(wbase + (ct*8 + 6 + k2)*512);
  __syncthreads();

  f32x4 sn = *(const f32x4*)(state + (size_t)gb*256 + c4);
  f16* const sa = &stA[(l >> 3)*520 + ((((l >> 1) & 3) << 4) + w)*8 + (l & 1)*4];
  { f16x4 h; h[0]=(f16)sn[0]; h[1]=(f16)sn[1]; h[2]=(f16)sn[2]; h[3]=(f16)sn[3]; *(f16x4*)sa = h; }
  lgkm_barrier();

  for (int i = 0; i < nsteps; ++i){
    const int t = t0 + i;
    const f16* p2 = P + (size_t)(i+2)*SL + gbo;
    const f16* p1 = P + (size_t)(i+1)*SL + gbo;
    const f16* p0 = P + (size_t)(i+0)*SL + gbo;

    // ---- keep-alive: pin persistent weights across the step loop ----
    #pragma unroll
    for (int ct = 0; ct < 8; ++ct)
      #pragma unroll
      for (int kt = 0; kt < 6; ++kt)
        asm volatile("" : "+v"(Wreg[ct][kt]));

    // ---- ALL P loads for this step issued upfront (pass below has no vmem,
    //      so nothing waits on these until phase 2: fully latency-hidden) ----
    const f16x4 cE2 = *(const f16x4*)(p2 + c4);
    const f16x4 cU  = *(const f16x4*)(p2 +  256 + c4);
    const f16x4 cR  = *(const f16x4*)(p2 +  512 + c4);
    const f16x4 cC  = *(const f16x4*)(p2 +  768 + c4);
    const f16x4 cNU = *(const f16x4*)(p2 + 1024 + c4);
    const f16x4 cNR = *(const f16x4*)(p2 + 1280 + c4);
    const f16x4 cNC = *(const f16x4*)(p2 + 1536 + c4);
    const f16x4 E0 = *(const f16x4*)(p0 + c4);
    const f16x4 E1 = *(const f16x4*)(p1 + c4);
    const f16x4 U1 = *(const f16x4*)(p1 + 256 + c4);
    const f16x4 R1 = *(const f16x4*)(p1 + 512 + c4);
    const f16x4 C1 = *(const f16x4*)(p1 + 768 + c4);
    const f16x4 U2 = *(const f16x4*)(p0 + 256 + c4);
    const f16x4 R2 = *(const f16x4*)(p0 + 512 + c4);
    const f16x4 C2 = *(const f16x4*)(p0 + 768 + c4);

    // ---- phase 1: batched A-fragments (8 back-to-back ds_reads, reused
    //      across all 4 quarters -- was 32 serialized read->MFMA chains) ----
    f16x8 av[8];
    #pragma unroll
    for (int kt = 0; kt < 8; ++kt) av[kt] = *(const f16x8*)&stA[kt*520 + l*8];

    #pragma unroll
    for (int qtr = 0; qtr < 4; ++qtr){
      const int c0 = qtr*2, c1 = qtr*2 + 1;
      f32x4 a0 = (f32x4){0.f,0.f,0.f,0.f}, a1 = a0;
      #pragma unroll
      for (int kt = 0; kt < 8; ++kt){
        f16x8 B0 = (kt < 6) ? Wreg[c0][kt]
                            : *(const f16x8*)&Wl[w*8192 + (c0*2 + (kt-6))*512 + l*8];
        f16x8 B1 = (kt < 6) ? Wreg[c1][kt]
                            : *(const f16x8*)&Wl[w*8192 + (c1*2 + (kt-6))*512 + l*8];
        a0 = mfma16(av[kt], B0, a0);
        a1 = mfma16(av[kt], B1, a1);
      }
      if (agrp < 2){
        #pragma unroll
        for (int j = 0; j < 4; ++j){
          qg16[(agrp*4 + j)*1032 + w*128 + c0*16 + arow] = (f16)a0[j];
          qg16[(agrp*4 + j)*1032 + w*128 + c1*16 + arow] = (f16)a1[j];
        }
      }
    }
    lgkm_barrier();

    // ---- scores + softmax (full wave on row w; P already in registers) ----
    const f16x4 qv = *(const f16x4*)&qg16[w*1032 + c4];
    const f16x4 qu = *(const f16x4*)&qg16[w*1032 + 256 + c4];
    const f16x4 qr = *(const f16x4*)&qg16[w*1032 + 512 + c4];
    const f16x4 qc = *(const f16x4*)&qg16[w*1032 + 768 + c4];
    float s0 = 0.f, s1 = 0.f, s2 = 0.f;
    #pragma unroll
    for (int j = 0; j < 4; ++j){
      const float qb = (float)qv[j] + bb[j];
      s0 += tanh_f((float)E0[j]  + qb) * lk[j];
      s1 += tanh_f((float)E1[j]  + qb) * lk[j];
      s2 += tanh_f((float)cE2[j] + qb) * lk[j];
    }
    #pragma unroll
    for (int off = 32; off; off >>= 1){
      s0 += __shfl_xor(s0, off);
      s1 += __shfl_xor(s1, off);
      s2 += __shfl_xor(s2, off);
    }
    const float mx = fmaxf(fmaxf(s0, s1), s2);
    const float x0 = __expf(s0 - mx), x1 = __expf(s1 - mx), x2 = __expf(s2 - mx);
    const float inv = 1.0f / (x0 + x1 + x2);
    const float pr0 = x0*inv, pr1 = x1*inv, pr2 = x2*inv;

    // ---- GRU (row w, 4 cols/lane, state in regs) ----
    #pragma unroll
    for (int j = 0; j < 4; ++j){
      const float geu = pr2*(float)cU[j] + pr1*(float)U1[j] + pr0*(float)U2[j];
      const float ger = pr2*(float)cR[j] + pr1*(float)R1[j] + pr0*(float)R2[j];
      const float gec = pr2*(float)cC[j] + pr1*(float)C1[j] + pr0*(float)C2[j];
      const float up   = sigmoid_f((float)qu[j] + geu + (float)cNU[j]);
      const float rp   = sigmoid_f((float)qr[j] + ger + (float)cNR[j]);
      const float cand = tanh_f(rp*(float)qc[j] + gec + (float)cNC[j]);
      sn[j] = (1.0f - up)*sn[j] + up*cand;
    }
    { f16x4 h; h[0]=(f16)sn[0]; h[1]=(f16)sn[1]; h[2]=(f16)sn[2]; h[3]=(f16)sn[3]; *(f16x4*)sa = h; }
    if (t == 255) *(f32x4*)(out + (size_t)gb*256 + c4) = sn;
    lgkm_barrier();
  }

  *(f32x4*)(state + (size_t)gb*256 + c4) = sn;
}

// ---------------------------------- launch ----------------------------------
extern "C" void kernel_launch(void* const* d_in, const int* in_sizes, int n_in,
                              void* d_out, int out_size, void* d_ws, size_t ws_size,
                              hipStream_t stream)
{
  const float* X  = (const float*)d_in[0];
  const float* EK = (const float*)d_in[1];
  const float* SK = (const float*)d_in[2];
  const float* BI = (const float*)d_in[3];
  const float* LK = (const float*)d_in[4];
  const float* RS = (const float*)d_in[5];
  const float* RE = (const float*)d_in[6];
  const float* NW = (const float*)d_in[7];
  float* out = (float*)d_out;
  char* ws = (char*)d_ws;

  const size_t slabB = 1024ull * 1792ull * 2ull;   // 3,670,016 B
  const size_t XhB   = 134217728ull;               // 1024*256*256 f16
  const size_t wB    = 917504ull + 524288ull + 1048576ull;
  int CT = 4;
  if      (ws_size >= 34ull*slabB + XhB + wB) CT = 32;
  else if (ws_size >= 18ull*slabB + XhB + wB) CT = 16;
  else if (ws_size >= 10ull*slabB + XhB + wB) CT = 8;

  f16* P = (f16*)ws;
  size_t poff = (size_t)(CT + 2) * slabB;
  f16* Xh    = (f16*)(ws + poff);
  f16* WcatT = (f16*)(ws + poff + XhB);
  f16* WsrF  = (f16*)(ws + poff + XhB + 917504ull);
  float* state = (float*)(ws + poff + XhB + 917504ull + 524288ull);

  hipMemsetAsync(state, 0, 1048576ull, stream);
  hipMemsetAsync(P, 0, 2ull*slabB, stream);        // zero "virtual" slabs t=-2,-1
  cast_x_kernel<<<32768, 256, 0, stream>>>(X, Xh);
  cast_w_kernel<<<2816, 256, 0, stream>>>(EK, RE, NW, SK, RS, WcatT, WsrF);

  const int nch = 256 / CT;
  for (int c = 0; c < nch; ++c){
    const int t0 = c * CT;
    const int t_start  = (c == 0) ? 0 : (t0 - 2);
    const int slab_off = (c == 0) ? 2 : 0;
    const int Mtiles = (((c == 0) ? CT : (CT + 2)) * 1024) / 128;
    gemm_f16_kernel<<<Mtiles * 14, 256, 0, stream>>>(
        Xh, WcatT, P + (size_t)slab_off * 1024 * 1792, Mtiles, t_start);
    recurrent_kernel<<<128, 512, 0, stream>>>(P, WsrF, BI, LK, state, out, t0, CT);
  }
}

// Round 14
// 1875.248 us; speedup vs baseline: 1.6250x; 1.3016x over previous
//
#include <hip/hip_runtime.h>

// AttentionRNN: B=1024, T=256, U=256.
//  P[t] = x_t @ [Wemb|Wre|Wnew] (fp16 MFMA GEMM reading fp32 X directly, CT chunks).
//  Recurrent v6 (= r11 + kt-outer batched pass, register-budget audited):
//  128 blocks x 8 rows x 8 waves. Weights persistent: kt0..5 in 192 regs/wave
//  (keep-alive pinned), kt6..7 in 128 KB LDS. Phase 1 is kt-outer: 8 pipelined
//  ds_reads of the state fragment, 8 independent acc chains (issue-bound MFMAs).
//  Budget: acc 32 + av-pipe 8 + cE2 2 + misc < 64 VGPR over the 192 weight regs
//  (r13's spill came from av[8]+15 P vecs+reg bias = ~270 > 256 cap).
//  Cold P: cE2 at step top; other 6 issued after the pass (consumed ~1.5K cyc
//  later in GRU). Warm P after barrier. lgkm-only barriers.

typedef _Float16 f16;
typedef _Float16 f16x8 __attribute__((ext_vector_type(8)));
typedef _Float16 f16x4 __attribute__((ext_vector_type(4)));
typedef float f32x4 __attribute__((ext_vector_type(4)));

static __device__ __forceinline__ f32x4 mfma16(f16x8 a, f16x8 b, f32x4 c){
  return __builtin_amdgcn_mfma_f32_16x16x32_f16(a, b, c, 0, 0, 0);
}
static __device__ __forceinline__ float sigmoid_f(float x){
  return 1.0f / (1.0f + __expf(-x));
}
static __device__ __forceinline__ float tanh_f(float x){
  float e = __expf(2.0f * x);
  return 1.0f - 2.0f / (e + 1.0f);   // stable
}
static __device__ __forceinline__ void lgkm_barrier(){
  asm volatile("s_waitcnt lgkmcnt(0)" ::: "memory");
  __builtin_amdgcn_s_barrier();
}

// ------------- cast weights to fp16 -------------
// WcatT rows: [0,256) Wemb^T, [256,1024) Wre^T, [1024,1792) Wnew^T  (N x K row-major)
// WsrF fragment-packed [ct64][kt8][lane64][e8]: col=ct*16+(lane&15), k=kt*32+((lane>>4)&3)*8+e
__global__ void cast_w_kernel(const float* __restrict__ EK, const float* __restrict__ RE,
    const float* __restrict__ NW, const float* __restrict__ SK, const float* __restrict__ RS,
    f16* __restrict__ WcatT, f16* __restrict__ WsrF){
  int tid = blockIdx.x * 256 + threadIdx.x;
  if (tid < 458752){
    int n = tid >> 8, k = tid & 255;
    float v;
    if (n < 256)       v = EK[k*256 + n];
    else if (n < 1024) v = RE[k*768 + (n-256)];
    else               v = NW[k*768 + (n-1024)];
    WcatT[n*256 + k] = (f16)v;
  } else {
    int idx = tid - 458752;            // 0..262143
    int e    = idx & 7;
    int lane = (idx >> 3) & 63;
    int kt   = (idx >> 9) & 7;
    int ct   = idx >> 12;              // 0..63
    int col  = ct*16 + (lane & 15);
    int k    = kt*32 + ((lane >> 4) & 3)*8 + e;
    float v = (col < 256) ? SK[k*256 + col] : RS[k*768 + (col-256)];
    WsrF[idx] = (f16)v;
  }
}

// ---- GEMM: C[r=tsl*1024+b][0:1792) = X[b][t_start+tsl][:] @ WcatT^T (fp32 A in-reg cast) ----
__global__ __launch_bounds__(256, 2) void gemm_f16_kernel(
    const float* __restrict__ X, const f16* __restrict__ Bm,
    f16* __restrict__ C, int Mtiles, int t_start)
{
  __shared__ f16 As[128*64];
  __shared__ f16 Bs[128*64];
  const int NT = 14;
  const int nwg = Mtiles * NT;
  int bid = blockIdx.x, wg = bid;
  if ((nwg & 7) == 0){ int cpx = nwg >> 3; wg = (bid & 7) * cpx + (bid >> 3); }
  const int mt = wg / NT, nt = wg % NT;
  const int tsl = mt >> 3;
  const int b0  = (mt & 7) * 128;
  const int t   = t_start + tsl;
  const int n0  = nt * 128;
  const int tid = threadIdx.x;
  const int l = tid & 63, wid = tid >> 6;
  const int wr = wid >> 1, wc = wid & 1;
  const int srow = tid >> 3;
  const int scol = (tid & 7) * 8;

  const size_t ASTR = 32ull * 65536ull;   // 32 b-rows in fp32 elems (T*U = 65536)
  const float* Ab = X + ((size_t)(b0 + srow) * 256 + t) * 256 + scol;
  const f16*   Bb = Bm + ((size_t)(n0 + srow)) * 256 + scol;

  f16x8 ra[4], rb[4];
  #pragma unroll
  for (int j = 0; j < 4; ++j){
    f32x4 v0 = *(const f32x4*)(Ab + (size_t)j * ASTR);
    f32x4 v1 = *(const f32x4*)(Ab + (size_t)j * ASTR + 4);
    f16x8 h;
    #pragma unroll
    for (int jj = 0; jj < 8; ++jj) h[jj] = (f16)((jj < 4) ? v0[jj] : v1[jj-4]);
    ra[j] = h;
    rb[j] = *(const f16x8*)(Bb + (size_t)j * 32 * 256);
  }

  f32x4 acc[4][4];
  #pragma unroll
  for (int mi = 0; mi < 4; ++mi)
    #pragma unroll
    for (int ni = 0; ni < 4; ++ni)
      acc[mi][ni] = (f32x4){0.f,0.f,0.f,0.f};

  for (int kt = 0; kt < 4; ++kt){
    #pragma unroll
    for (int j = 0; j < 4; ++j){
      int row = srow + j*32;
      int e = (row*64 + scol) ^ ((row & 7) << 3);
      *(f16x8*)&As[e] = ra[j];
      *(f16x8*)&Bs[e] = rb[j];
    }
    __syncthreads();
    if (kt < 3){
      #pragma unroll
      for (int j = 0; j < 4; ++j){
        f32x4 v0 = *(const f32x4*)(Ab + (kt+1)*64 + (size_t)j * ASTR);
        f32x4 v1 = *(const f32x4*)(Ab + (kt+1)*64 + (size_t)j * ASTR + 4);
        f16x8 h;
        #pragma unroll
        for (int jj = 0; jj < 8; ++jj) h[jj] = (f16)((jj < 4) ? v0[jj] : v1[jj-4]);
        ra[j] = h;
        rb[j] = *(const f16x8*)(Bb + (kt+1)*64 + (size_t)j * 32 * 256);
      }
    }
    #pragma unroll
    for (int kk = 0; kk < 2; ++kk){
      f16x8 af[4], bfr[4];
      #pragma unroll
      for (int mi = 0; mi < 4; ++mi){
        int row = wr*64 + mi*16 + (l & 15);
        int e = (row*64 + kk*32 + (l >> 4)*8) ^ ((row & 7) << 3);
        af[mi] = *(const f16x8*)&As[e];
      }
      #pragma unroll
      for (int ni = 0; ni < 4; ++ni){
        int row = wc*64 + ni*16 + (l & 15);
        int e = (row*64 + kk*32 + (l >> 4)*8) ^ ((row & 7) << 3);
        bfr[ni] = *(const f16x8*)&Bs[e];
      }
      #pragma unroll
      for (int mi = 0; mi < 4; ++mi)
        #pragma unroll
        for (int ni = 0; ni < 4; ++ni)
          acc[mi][ni] = mfma16(af[mi], bfr[ni], acc[mi][ni]);
    }
    __syncthreads();
  }
  const size_t m0 = (size_t)mt * 128;
  #pragma unroll
  for (int mi = 0; mi < 4; ++mi){
    #pragma unroll
    for (int ni = 0; ni < 4; ++ni){
      int col = n0 + wc*64 + ni*16 + (l & 15);
      size_t row = m0 + wr*64 + mi*16 + ((l >> 4) * 4);
      #pragma unroll
      for (int j = 0; j < 4; ++j)
        C[(row + j) * 1792 + col] = (f16)acc[mi][ni][j];
    }
  }
}

// ---------- recurrent v6: 128 blocks x 8 rows, 512 threads (8 waves) ----------
__global__ __launch_bounds__(512, 1) void recurrent_kernel(
    const f16* __restrict__ P, const f16* __restrict__ WsrF,
    const float* __restrict__ bias, const float* __restrict__ Lk,
    float* __restrict__ state, float* __restrict__ out,
    int t0, int nsteps)
{
  __shared__ f16 Wl[8*8192];             // weights kt6..7: 128 KB
  __shared__ f16 qg16[8*1032];           // qg as f16: [row][1032]
  __shared__ f16 stA[8*520];             // state f16, fragment-major [kt][lane][8]
  __shared__ __align__(16) float sb[256];
  __shared__ __align__(16) float sl[256];

  const int tid = threadIdx.x;
  const int l = tid & 63, w = tid >> 6;  // 8 waves, wave w owns row w
  const int r0 = blockIdx.x * 8;
  const int arow = l & 15, agrp = l >> 4;
  const int c4 = l * 4;
  const int gb = r0 + w;
  const size_t SL = 1024ull*1792ull;
  const size_t gbo = (size_t)gb*1792;

  if (tid < 256){ sb[tid] = bias[tid]; sl[tid] = Lk[tid]; }
  for (int j = tid; j < 8*520; j += 512) stA[j] = (f16)0.f;

  // ---- persistent weights: kt0..5 -> 192 regs/wave ----
  const f16* const wbase = WsrF + (size_t)w*32768 + l*8;   // wave's 8 ct-tiles
  f16x8 Wreg[8][6];
  #pragma unroll
  for (int ct = 0; ct < 8; ++ct)
    #pragma unroll
    for (int kt = 0; kt < 6; ++kt)
      Wreg[ct][kt] = *(const f16x8*)(wbase + (ct*8 + kt)*512);
  // ---- kt6..7 -> LDS (128 KB, loaded once) ----
  #pragma unroll
  for (int ct = 0; ct < 8; ++ct)
    #pragma unroll
    for (int k2 = 0; k2 < 2; ++k2)
      *(f16x8*)&Wl[w*8192 + (ct*2 + k2)*512 + l*8] =
          *(const f16x8*)(wbase + (ct*8 + 6 + k2)*512);
  __syncthreads();

  f32x4 sn = *(const f32x4*)(state + (size_t)gb*256 + c4);
  f16* const sa = &stA[(l >> 3)*520 + ((((l >> 1) & 3) << 4) + w)*8 + (l & 1)*4];
  { f16x4 h; h[0]=(f16)sn[0]; h[1]=(f16)sn[1]; h[2]=(f16)sn[2]; h[3]=(f16)sn[3]; *(f16x4*)sa = h; }
  lgkm_barrier();

  for (int i = 0; i < nsteps; ++i){
    const int t = t0 + i;
    const f16* p2 = P + (size_t)(i+2)*SL + gbo;
    const f16* p1 = P + (size_t)(i+1)*SL + gbo;
    const f16* p0 = P + (size_t)(i+0)*SL + gbo;

    // ---- keep-alive: pin persistent weights across the step loop ----
    #pragma unroll
    for (int ct = 0; ct < 8; ++ct)
      #pragma unroll
      for (int kt = 0; kt < 6; ++kt)
        asm volatile("" : "+v"(Wreg[ct][kt]));

    // ---- earliest-needed cold P load only (scores): keeps regs low ----
    const f16x4 cE2 = *(const f16x4*)(p2 + c4);

    // ---- phase 1: kt-outer pass, 8 pipelined ds_reads, 8 indep acc chains ----
    f32x4 acc[8];
    #pragma unroll
    for (int c = 0; c < 8; ++c) acc[c] = (f32x4){0.f,0.f,0.f,0.f};
    {
      f16x8 av0 = *(const f16x8*)&stA[0*520 + l*8];
      f16x8 av1 = *(const f16x8*)&stA[1*520 + l*8];
      #pragma unroll
      for (int kt = 0; kt < 8; ++kt){
        const f16x8 avc = (kt & 1) ? av1 : av0;
        if (kt < 6){
          f16x8 nx = *(const f16x8*)&stA[(kt+2)*520 + l*8];
          if (kt & 1) av1 = nx; else av0 = nx;
        }
        #pragma unroll
        for (int ct = 0; ct < 8; ++ct){
          f16x8 B = (kt < 6) ? Wreg[ct][kt]
                             : *(const f16x8*)&Wl[w*8192 + (ct*2 + (kt-6))*512 + l*8];
          acc[ct] = mfma16(avc, B, acc[ct]);
        }
      }
    }

    // ---- remaining cold P loads: consumed in GRU, ~1.5K cycles away ----
    const f16x4 cU  = *(const f16x4*)(p2 +  256 + c4);
    const f16x4 cR  = *(const f16x4*)(p2 +  512 + c4);
    const f16x4 cC  = *(const f16x4*)(p2 +  768 + c4);
    const f16x4 cNU = *(const f16x4*)(p2 + 1024 + c4);
    const f16x4 cNR = *(const f16x4*)(p2 + 1280 + c4);
    const f16x4 cNC = *(const f16x4*)(p2 + 1536 + c4);

    if (agrp < 2){
      #pragma unroll
      for (int ct = 0; ct < 8; ++ct){
        #pragma unroll
        for (int j = 0; j < 4; ++j)
          qg16[(agrp*4 + j)*1032 + w*128 + ct*16 + arow] = (f16)acc[ct][j];
      }
    }
    lgkm_barrier();

    // ---- warm P loads (slabs i, i+1: L2-resident from prior steps) ----
    const f16x4 E0 = *(const f16x4*)(p0 + c4);
    const f16x4 E1 = *(const f16x4*)(p1 + c4);
    const f16x4 U1 = *(const f16x4*)(p1 + 256 + c4);
    const f16x4 R1 = *(const f16x4*)(p1 + 512 + c4);
    const f16x4 C1 = *(const f16x4*)(p1 + 768 + c4);
    const f16x4 U2 = *(const f16x4*)(p0 + 256 + c4);
    const f16x4 R2 = *(const f16x4*)(p0 + 512 + c4);
    const f16x4 C2 = *(const f16x4*)(p0 + 768 + c4);

    // ---- scores + softmax (full wave on row w) ----
    const f16x4 qv = *(const f16x4*)&qg16[w*1032 + c4];
    const f16x4 qu = *(const f16x4*)&qg16[w*1032 + 256 + c4];
    const f16x4 qr = *(const f16x4*)&qg16[w*1032 + 512 + c4];
    const f16x4 qc = *(const f16x4*)&qg16[w*1032 + 768 + c4];
    const f32x4 bb = *(const f32x4*)&sb[c4];
    const f32x4 lk = *(const f32x4*)&sl[c4];
    float s0 = 0.f, s1 = 0.f, s2 = 0.f;
    #pragma unroll
    for (int j = 0; j < 4; ++j){
      const float qb = (float)qv[j] + bb[j];
      s0 += tanh_f((float)E0[j]  + qb) * lk[j];
      s1 += tanh_f((float)E1[j]  + qb) * lk[j];
      s2 += tanh_f((float)cE2[j] + qb) * lk[j];
    }
    #pragma unroll
    for (int off = 32; off; off >>= 1){
      s0 += __shfl_xor(s0, off);
      s1 += __shfl_xor(s1, off);
      s2 += __shfl_xor(s2, off);
    }
    const float mx = fmaxf(fmaxf(s0, s1), s2);
    const float x0 = __expf(s0 - mx), x1 = __expf(s1 - mx), x2 = __expf(s2 - mx);
    const float inv = 1.0f / (x0 + x1 + x2);
    const float pr0 = x0*inv, pr1 = x1*inv, pr2 = x2*inv;

    // ---- GRU (row w, 4 cols/lane, state in regs) ----
    #pragma unroll
    for (int j = 0; j < 4; ++j){
      const float geu = pr2*(float)cU[j] + pr1*(float)U1[j] + pr0*(float)U2[j];
      const float ger = pr2*(float)cR[j] + pr1*(float)R1[j] + pr0*(float)R2[j];
      const float gec = pr2*(float)cC[j] + pr1*(float)C1[j] + pr0*(float)C2[j];
      const float up   = sigmoid_f((float)qu[j] + geu + (float)cNU[j]);
      const float rp   = sigmoid_f((float)qr[j] + ger + (float)cNR[j]);
      const float cand = tanh_f(rp*(float)qc[j] + gec + (float)cNC[j]);
      sn[j] = (1.0f - up)*sn[j] + up*cand;
    }
    { f16x4 h; h[0]=(f16)sn[0]; h[1]=(f16)sn[1]; h[2]=(f16)sn[2]; h[3]=(f16)sn[3]; *(f16x4*)sa = h; }
    if (t == 255) *(f32x4*)(out + (size_t)gb*256 + c4) = sn;
    lgkm_barrier();
  }

  *(f32x4*)(state + (size_t)gb*256 + c4) = sn;
}

// ---------------------------------- launch ----------------------------------
extern "C" void kernel_launch(void* const* d_in, const int* in_sizes, int n_in,
                              void* d_out, int out_size, void* d_ws, size_t ws_size,
                              hipStream_t stream)
{
  const float* X  = (const float*)d_in[0];
  const float* EK = (const float*)d_in[1];
  const float* SK = (const float*)d_in[2];
  const float* BI = (const float*)d_in[3];
  const float* LK = (const float*)d_in[4];
  const float* RS = (const float*)d_in[5];
  const float* RE = (const float*)d_in[6];
  const float* NW = (const float*)d_in[7];
  float* out = (float*)d_out;
  char* ws = (char*)d_ws;

  const size_t slabB = 1024ull * 1792ull * 2ull;   // 3,670,016 B
  const size_t wB    = 917504ull + 524288ull + 1048576ull;
  int CT = 4;
  if      (ws_size >= 34ull*slabB + wB) CT = 32;
  else if (ws_size >= 18ull*slabB + wB) CT = 16;
  else if (ws_size >= 10ull*slabB + wB) CT = 8;

  f16* P = (f16*)ws;
  size_t poff = (size_t)(CT + 2) * slabB;
  f16* WcatT = (f16*)(ws + poff);
  f16* WsrF  = (f16*)(ws + poff + 917504ull);
  float* state = (float*)(ws + poff + 917504ull + 524288ull);

  hipMemsetAsync(state, 0, 1048576ull, stream);
  hipMemsetAsync(P, 0, 2ull*slabB, stream);        // zero "virtual" slabs t=-2,-1
  cast_w_kernel<<<2816, 256, 0, stream>>>(EK, RE, NW, SK, RS, WcatT, WsrF);

  const int nch = 256 / CT;
  for (int c = 0; c < nch; ++c){
    const int t0 = c * CT;
    const int t_start  = (c == 0) ? 0 : (t0 - 2);
    const int slab_off = (c == 0) ? 2 : 0;
    const int Mtiles = (((c == 0) ? CT : (CT + 2)) * 1024) / 128;
    gemm_f16_kernel<<<Mtiles * 14, 256, 0, stream>>>(
        X, WcatT, P + (size_t)slab_off * 1024 * 1792, Mtiles, t_start);
    recurrent_kernel<<<128, 512, 0, stream>>>(P, WsrF, BI, LK, state, out, t0, CT);
  }
}

// Round 15
// 1723.954 us; speedup vs baseline: 1.7676x; 1.0878x over previous
//
#include <hip/hip_runtime.h>

// AttentionRNN: B=1024, T=256, U=256.
//  P[t] = x_t @ [Wemb|Wre|Wnew] (fp16 MFMA GEMM reading fp32 X directly, CT chunks).
//  Recurrent v7 (all-CU spread): 256 blocks x 4 rows x 8 waves. Per-CU VALU work
//  (the r14-measured bottleneck: 48% VALUBusy on active CUs) halves; MFMA pipe
//  (20% busy) absorbs the extra M-waste. Weights persistent per block: kt0..5 in
//  192 regs/wave (keep-alive pinned), kt6..7 in 128 KB LDS. Phase 2 splits each
//  row across a wave pair (2 cols/lane), score partials combined via LDS.
//  3 lgkm-only barriers/step. CT=64 chunks (ws allows; half the dispatches).

typedef _Float16 f16;
typedef _Float16 f16x8 __attribute__((ext_vector_type(8)));
typedef _Float16 f16x4 __attribute__((ext_vector_type(4)));
typedef _Float16 f16x2 __attribute__((ext_vector_type(2)));
typedef float f32x4 __attribute__((ext_vector_type(4)));
typedef float f32x2 __attribute__((ext_vector_type(2)));

static __device__ __forceinline__ f32x4 mfma16(f16x8 a, f16x8 b, f32x4 c){
  return __builtin_amdgcn_mfma_f32_16x16x32_f16(a, b, c, 0, 0, 0);
}
static __device__ __forceinline__ float sigmoid_f(float x){
  return 1.0f / (1.0f + __expf(-x));
}
static __device__ __forceinline__ float tanh_f(float x){
  float e = __expf(2.0f * x);
  return 1.0f - 2.0f / (e + 1.0f);   // stable
}
static __device__ __forceinline__ void lgkm_barrier(){
  asm volatile("s_waitcnt lgkmcnt(0)" ::: "memory");
  __builtin_amdgcn_s_barrier();
}

// ------------- cast weights to fp16 -------------
// WcatT rows: [0,256) Wemb^T, [256,1024) Wre^T, [1024,1792) Wnew^T  (N x K row-major)
// WsrF fragment-packed [ct64][kt8][lane64][e8]: col=ct*16+(lane&15), k=kt*32+((lane>>4)&3)*8+e
__global__ void cast_w_kernel(const float* __restrict__ EK, const float* __restrict__ RE,
    const float* __restrict__ NW, const float* __restrict__ SK, const float* __restrict__ RS,
    f16* __restrict__ WcatT, f16* __restrict__ WsrF){
  int tid = blockIdx.x * 256 + threadIdx.x;
  if (tid < 458752){
    int n = tid >> 8, k = tid & 255;
    float v;
    if (n < 256)       v = EK[k*256 + n];
    else if (n < 1024) v = RE[k*768 + (n-256)];
    else               v = NW[k*768 + (n-1024)];
    WcatT[n*256 + k] = (f16)v;
  } else {
    int idx = tid - 458752;            // 0..262143
    int e    = idx & 7;
    int lane = (idx >> 3) & 63;
    int kt   = (idx >> 9) & 7;
    int ct   = idx >> 12;              // 0..63
    int col  = ct*16 + (lane & 15);
    int k    = kt*32 + ((lane >> 4) & 3)*8 + e;
    float v = (col < 256) ? SK[k*256 + col] : RS[k*768 + (col-256)];
    WsrF[idx] = (f16)v;
  }
}

// ---- GEMM: C[r=tsl*1024+b][0:1792) = X[b][t_start+tsl][:] @ WcatT^T (fp32 A in-reg cast) ----
__global__ __launch_bounds__(256, 2) void gemm_f16_kernel(
    const float* __restrict__ X, const f16* __restrict__ Bm,
    f16* __restrict__ C, int Mtiles, int t_start)
{
  __shared__ f16 As[128*64];
  __shared__ f16 Bs[128*64];
  const int NT = 14;
  const int nwg = Mtiles * NT;
  int bid = blockIdx.x, wg = bid;
  if ((nwg & 7) == 0){ int cpx = nwg >> 3; wg = (bid & 7) * cpx + (bid >> 3); }
  const int mt = wg / NT, nt = wg % NT;
  const int tsl = mt >> 3;
  const int b0  = (mt & 7) * 128;
  const int t   = t_start + tsl;
  const int n0  = nt * 128;
  const int tid = threadIdx.x;
  const int l = tid & 63, wid = tid >> 6;
  const int wr = wid >> 1, wc = wid & 1;
  const int srow = tid >> 3;
  const int scol = (tid & 7) * 8;

  const size_t ASTR = 32ull * 65536ull;   // 32 b-rows in fp32 elems (T*U = 65536)
  const float* Ab = X + ((size_t)(b0 + srow) * 256 + t) * 256 + scol;
  const f16*   Bb = Bm + ((size_t)(n0 + srow)) * 256 + scol;

  f16x8 ra[4], rb[4];
  #pragma unroll
  for (int j = 0; j < 4; ++j){
    f32x4 v0 = *(const f32x4*)(Ab + (size_t)j * ASTR);
    f32x4 v1 = *(const f32x4*)(Ab + (size_t)j * ASTR + 4);
    f16x8 h;
    #pragma unroll
    for (int jj = 0; jj < 8; ++jj) h[jj] = (f16)((jj < 4) ? v0[jj] : v1[jj-4]);
    ra[j] = h;
    rb[j] = *(const f16x8*)(Bb + (size_t)j * 32 * 256);
  }

  f32x4 acc[4][4];
  #pragma unroll
  for (int mi = 0; mi < 4; ++mi)
    #pragma unroll
    for (int ni = 0; ni < 4; ++ni)
      acc[mi][ni] = (f32x4){0.f,0.f,0.f,0.f};

  for (int kt = 0; kt < 4; ++kt){
    #pragma unroll
    for (int j = 0; j < 4; ++j){
      int row = srow + j*32;
      int e = (row*64 + scol) ^ ((row & 7) << 3);
      *(f16x8*)&As[e] = ra[j];
      *(f16x8*)&Bs[e] = rb[j];
    }
    __syncthreads();
    if (kt < 3){
      #pragma unroll
      for (int j = 0; j < 4; ++j){
        f32x4 v0 = *(const f32x4*)(Ab + (kt+1)*64 + (size_t)j * ASTR);
        f32x4 v1 = *(const f32x4*)(Ab + (kt+1)*64 + (size_t)j * ASTR + 4);
        f16x8 h;
        #pragma unroll
        for (int jj = 0; jj < 8; ++jj) h[jj] = (f16)((jj < 4) ? v0[jj] : v1[jj-4]);
        ra[j] = h;
        rb[j] = *(const f16x8*)(Bb + (kt+1)*64 + (size_t)j * 32 * 256);
      }
    }
    #pragma unroll
    for (int kk = 0; kk < 2; ++kk){
      f16x8 af[4], bfr[4];
      #pragma unroll
      for (int mi = 0; mi < 4; ++mi){
        int row = wr*64 + mi*16 + (l & 15);
        int e = (row*64 + kk*32 + (l >> 4)*8) ^ ((row & 7) << 3);
        af[mi] = *(const f16x8*)&As[e];
      }
      #pragma unroll
      for (int ni = 0; ni < 4; ++ni){
        int row = wc*64 + ni*16 + (l & 15);
        int e = (row*64 + kk*32 + (l >> 4)*8) ^ ((row & 7) << 3);
        bfr[ni] = *(const f16x8*)&Bs[e];
      }
      #pragma unroll
      for (int mi = 0; mi < 4; ++mi)
        #pragma unroll
        for (int ni = 0; ni < 4; ++ni)
          acc[mi][ni] = mfma16(af[mi], bfr[ni], acc[mi][ni]);
    }
    __syncthreads();
  }
  const size_t m0 = (size_t)mt * 128;
  #pragma unroll
  for (int mi = 0; mi < 4; ++mi){
    #pragma unroll
    for (int ni = 0; ni < 4; ++ni){
      int col = n0 + wc*64 + ni*16 + (l & 15);
      size_t row = m0 + wr*64 + mi*16 + ((l >> 4) * 4);
      #pragma unroll
      for (int j = 0; j < 4; ++j)
        C[(row + j) * 1792 + col] = (f16)acc[mi][ni][j];
    }
  }
}

// ---------- recurrent v7: 256 blocks x 4 rows, 512 threads (8 waves) ----------
__global__ __launch_bounds__(512, 1) void recurrent_kernel(
    const f16* __restrict__ P, const f16* __restrict__ WsrF,
    const float* __restrict__ bias, const float* __restrict__ Lk,
    float* __restrict__ state, float* __restrict__ out,
    int t0, int nsteps)
{
  __shared__ f16 Wl[8*8192];             // weights kt6..7: 128 KB
  __shared__ f16 qg16[4*1032];           // qg as f16: [row j][1032]
  __shared__ f16 stA[8*520];             // state f16, fragment-major [kt][lane][8]
  __shared__ __align__(16) float sb[256];
  __shared__ __align__(16) float sl[256];
  __shared__ float sp[4][2][3];          // score partials [row][half][slot]

  const int tid = threadIdx.x;
  const int l = tid & 63, w = tid >> 6;  // 8 waves
  const int r0 = blockIdx.x * 4;
  const int arow = l & 15, agrp = l >> 4;
  const int r = w >> 1, h = w & 1;       // row 0..3, half 0..1 (wave pair per row)
  const int c2 = h*128 + l*2;            // 2 cols/lane
  const int gb = r0 + r;
  const size_t SL = 1024ull*1792ull;
  const size_t gbo = (size_t)gb*1792;

  if (tid < 256){ sb[tid] = bias[tid]; sl[tid] = Lk[tid]; }
  for (int j = tid; j < 8*520; j += 512) stA[j] = (f16)0.f;

  // ---- persistent weights: kt0..5 -> 192 regs/wave ----
  const f16* const wbase = WsrF + (size_t)w*32768 + l*8;   // wave's 8 ct-tiles
  f16x8 Wreg[8][6];
  #pragma unroll
  for (int ct = 0; ct < 8; ++ct)
    #pragma unroll
    for (int kt = 0; kt < 6; ++kt)
      Wreg[ct][kt] = *(const f16x8*)(wbase + (ct*8 + kt)*512);
  // ---- kt6..7 -> LDS (128 KB, loaded once) ----
  #pragma unroll
  for (int ct = 0; ct < 8; ++ct)
    #pragma unroll
    for (int k2 = 0; k2 < 2; ++k2)
      *(f16x8*)&Wl[w*8192 + (ct*2 + k2)*512 + l*8] =
          *(const f16x8*)(wbase + (ct*8 + 6 + k2)*512);
  __syncthreads();

  // state: 2 cols/lane, rows 0..3 of stA valid (rest stay zero)
  f32x2 sn = *(const f32x2*)(state + (size_t)gb*256 + c2);
  const int kt0 = c2 >> 5, g0 = (c2 >> 3) & 3, e0 = c2 & 7;
  f16* const sa = &stA[kt0*520 + (g0*16 + r)*8 + e0];
  { f16x2 hh; hh[0]=(f16)sn[0]; hh[1]=(f16)sn[1]; *(f16x2*)sa = hh; }
  lgkm_barrier();

  for (int i = 0; i < nsteps; ++i){
    const int t = t0 + i;
    const f16* p2 = P + (size_t)(i+2)*SL + gbo;
    const f16* p1 = P + (size_t)(i+1)*SL + gbo;
    const f16* p0 = P + (size_t)(i+0)*SL + gbo;

    // ---- keep-alive: pin persistent weights across the step loop ----
    #pragma unroll
    for (int ct = 0; ct < 8; ++ct)
      #pragma unroll
      for (int kt = 0; kt < 6; ++kt)
        asm volatile("" : "+v"(Wreg[ct][kt]));

    // ---- cold (slab i+2, HBM) + scores-critical warm loads, upfront ----
    const f16x2 cE2 = *(const f16x2*)(p2 + c2);
    const f16x2 cU  = *(const f16x2*)(p2 +  256 + c2);
    const f16x2 cR  = *(const f16x2*)(p2 +  512 + c2);
    const f16x2 cC  = *(const f16x2*)(p2 +  768 + c2);
    const f16x2 cNU = *(const f16x2*)(p2 + 1024 + c2);
    const f16x2 cNR = *(const f16x2*)(p2 + 1280 + c2);
    const f16x2 cNC = *(const f16x2*)(p2 + 1536 + c2);
    const f16x2 E0  = *(const f16x2*)(p0 + c2);
    const f16x2 E1  = *(const f16x2*)(p1 + c2);

    // ---- phase 1: kt-outer pass, 8 pipelined ds_reads, 8 indep acc chains ----
    f32x4 acc[8];
    #pragma unroll
    for (int c = 0; c < 8; ++c) acc[c] = (f32x4){0.f,0.f,0.f,0.f};
    {
      f16x8 av0 = *(const f16x8*)&stA[0*520 + l*8];
      f16x8 av1 = *(const f16x8*)&stA[1*520 + l*8];
      #pragma unroll
      for (int kt = 0; kt < 8; ++kt){
        const f16x8 avc = (kt & 1) ? av1 : av0;
        if (kt < 6){
          f16x8 nx = *(const f16x8*)&stA[(kt+2)*520 + l*8];
          if (kt & 1) av1 = nx; else av0 = nx;
        }
        #pragma unroll
        for (int ct = 0; ct < 8; ++ct){
          f16x8 B = (kt < 6) ? Wreg[ct][kt]
                             : *(const f16x8*)&Wl[w*8192 + (ct*2 + (kt-6))*512 + l*8];
          acc[ct] = mfma16(avc, B, acc[ct]);
        }
      }
    }

    // qg write: keep C rows 0..3 only (agrp==0); col = w*128 + ct*16 + arow
    if (agrp == 0){
      #pragma unroll
      for (int ct = 0; ct < 8; ++ct){
        #pragma unroll
        for (int j = 0; j < 4; ++j)
          qg16[j*1032 + w*128 + ct*16 + arow] = (f16)acc[ct][j];
      }
    }
    lgkm_barrier();

    // ---- remaining warm loads (GRU operands, consumed after scores) ----
    const f16x2 U1 = *(const f16x2*)(p1 + 256 + c2);
    const f16x2 R1 = *(const f16x2*)(p1 + 512 + c2);
    const f16x2 C1 = *(const f16x2*)(p1 + 768 + c2);
    const f16x2 U2 = *(const f16x2*)(p0 + 256 + c2);
    const f16x2 R2 = *(const f16x2*)(p0 + 512 + c2);
    const f16x2 C2 = *(const f16x2*)(p0 + 768 + c2);

    // ---- phase 2a: score partials (row r, 128 cols per wave, 2/lane) ----
    {
      const f16x2 qv = *(const f16x2*)&qg16[r*1032 + c2];
      const f32x2 bb = *(const f32x2*)&sb[c2];
      const f32x2 lk = *(const f32x2*)&sl[c2];
      float s0 = 0.f, s1 = 0.f, s2 = 0.f;
      #pragma unroll
      for (int j = 0; j < 2; ++j){
        const float qb = (float)qv[j] + bb[j];
        s0 += tanh_f((float)E0[j]  + qb) * lk[j];
        s1 += tanh_f((float)E1[j]  + qb) * lk[j];
        s2 += tanh_f((float)cE2[j] + qb) * lk[j];
      }
      #pragma unroll
      for (int off = 32; off; off >>= 1){
        s0 += __shfl_xor(s0, off);
        s1 += __shfl_xor(s1, off);
        s2 += __shfl_xor(s2, off);
      }
      if (l == 0){ sp[r][h][0] = s0; sp[r][h][1] = s1; sp[r][h][2] = s2; }
    }
    lgkm_barrier();

    // ---- phase 2b: softmax (from partials, redundant per lane) + GRU ----
    {
      const float s0 = sp[r][0][0] + sp[r][1][0];
      const float s1 = sp[r][0][1] + sp[r][1][1];
      const float s2 = sp[r][0][2] + sp[r][1][2];
      const float mx = fmaxf(fmaxf(s0, s1), s2);
      const float x0 = __expf(s0 - mx), x1 = __expf(s1 - mx), x2 = __expf(s2 - mx);
      const float inv = 1.0f / (x0 + x1 + x2);
      const float pr0 = x0*inv, pr1 = x1*inv, pr2 = x2*inv;

      const f16x2 qu = *(const f16x2*)&qg16[r*1032 + 256 + c2];
      const f16x2 qr = *(const f16x2*)&qg16[r*1032 + 512 + c2];
      const f16x2 qc = *(const f16x2*)&qg16[r*1032 + 768 + c2];
      #pragma unroll
      for (int j = 0; j < 2; ++j){
        const float geu = pr2*(float)cU[j] + pr1*(float)U1[j] + pr0*(float)U2[j];
        const float ger = pr2*(float)cR[j] + pr1*(float)R1[j] + pr0*(float)R2[j];
        const float gec = pr2*(float)cC[j] + pr1*(float)C1[j] + pr0*(float)C2[j];
        const float up   = sigmoid_f((float)qu[j] + geu + (float)cNU[j]);
        const float rp   = sigmoid_f((float)qr[j] + ger + (float)cNR[j]);
        const float cand = tanh_f(rp*(float)qc[j] + gec + (float)cNC[j]);
        sn[j] = (1.0f - up)*sn[j] + up*cand;
      }
      { f16x2 hh; hh[0]=(f16)sn[0]; hh[1]=(f16)sn[1]; *(f16x2*)sa = hh; }
      if (t == 255) *(f32x2*)(out + (size_t)gb*256 + c2) = sn;
    }
    lgkm_barrier();
  }

  *(f32x2*)(state + (size_t)gb*256 + c2) = sn;
}

// ---------------------------------- launch ----------------------------------
extern "C" void kernel_launch(void* const* d_in, const int* in_sizes, int n_in,
                              void* d_out, int out_size, void* d_ws, size_t ws_size,
                              hipStream_t stream)
{
  const float* X  = (const float*)d_in[0];
  const float* EK = (const float*)d_in[1];
  const float* SK = (const float*)d_in[2];
  const float* BI = (const float*)d_in[3];
  const float* LK = (const float*)d_in[4];
  const float* RS = (const float*)d_in[5];
  const float* RE = (const float*)d_in[6];
  const float* NW = (const float*)d_in[7];
  float* out = (float*)d_out;
  char* ws = (char*)d_ws;

  const size_t slabB = 1024ull * 1792ull * 2ull;   // 3,670,016 B
  const size_t wB    = 917504ull + 524288ull + 1048576ull;
  int CT = 4;
  if      (ws_size >= 66ull*slabB + wB) CT = 64;
  else if (ws_size >= 34ull*slabB + wB) CT = 32;
  else if (ws_size >= 18ull*slabB + wB) CT = 16;
  else if (ws_size >= 10ull*slabB + wB) CT = 8;

  f16* P = (f16*)ws;
  size_t poff = (size_t)(CT + 2) * slabB;
  f16* WcatT = (f16*)(ws + poff);
  f16* WsrF  = (f16*)(ws + poff + 917504ull);
  float* state = (float*)(ws + poff + 917504ull + 524288ull);

  hipMemsetAsync(state, 0, 1048576ull, stream);
  hipMemsetAsync(P, 0, 2ull*slabB, stream);        // zero "virtual" slabs t=-2,-1
  cast_w_kernel<<<2816, 256, 0, stream>>>(EK, RE, NW, SK, RS, WcatT, WsrF);

  const int nch = 256 / CT;
  for (int c = 0; c < nch; ++c){
    const int t0 = c * CT;
    const int t_start  = (c == 0) ? 0 : (t0 - 2);
    const int slab_off = (c == 0) ? 2 : 0;
    const int Mtiles = (((c == 0) ? CT : (CT + 2)) * 1024) / 128;
    gemm_f16_kernel<<<Mtiles * 14, 256, 0, stream>>>(
        X, WcatT, P + (size_t)slab_off * 1024 * 1792, Mtiles, t_start);
    recurrent_kernel<<<256, 512, 0, stream>>>(P, WsrF, BI, LK, state, out, t0, CT);
  }
}

// Round 16
// 1708.470 us; speedup vs baseline: 1.7836x; 1.0091x over previous
//
#include <hip/hip_runtime.h>

// AttentionRNN: B=1024, T=256, U=256.
//  P[t] = x_t @ [Wemb|Wre|Wnew] (fp16 MFMA GEMM reading fp32 X directly, CT chunks).
//  Recurrent v8 (= v7 all-CU spread, spill-free budget): 256 blocks x 4 rows x
//  8 waves. Weights persistent: kt0..5 in 192 regs/wave (keep-alive pinned),
//  kt6..7 in 128 KB LDS. Phase 1 = two half-passes (acc[4], kt-outer, pipelined
//  av) -> peak regs ~230 < 256 (r15's acc[8]+15 P regs spilled: WRITE 72MB).
//  Cold GRU loads deferred to after phase 1. Phase 2 splits each row across a
//  wave pair (2 cols/lane), partials combined via LDS. 3 lgkm barriers/step.

typedef _Float16 f16;
typedef _Float16 f16x8 __attribute__((ext_vector_type(8)));
typedef _Float16 f16x4 __attribute__((ext_vector_type(4)));
typedef _Float16 f16x2 __attribute__((ext_vector_type(2)));
typedef float f32x4 __attribute__((ext_vector_type(4)));
typedef float f32x2 __attribute__((ext_vector_type(2)));

static __device__ __forceinline__ f32x4 mfma16(f16x8 a, f16x8 b, f32x4 c){
  return __builtin_amdgcn_mfma_f32_16x16x32_f16(a, b, c, 0, 0, 0);
}
static __device__ __forceinline__ float sigmoid_f(float x){
  return 1.0f / (1.0f + __expf(-x));
}
static __device__ __forceinline__ float tanh_f(float x){
  float e = __expf(2.0f * x);
  return 1.0f - 2.0f / (e + 1.0f);   // stable
}
static __device__ __forceinline__ void lgkm_barrier(){
  asm volatile("s_waitcnt lgkmcnt(0)" ::: "memory");
  __builtin_amdgcn_s_barrier();
}

// ------------- cast weights to fp16 -------------
// WcatT rows: [0,256) Wemb^T, [256,1024) Wre^T, [1024,1792) Wnew^T  (N x K row-major)
// WsrF fragment-packed [ct64][kt8][lane64][e8]: col=ct*16+(lane&15), k=kt*32+((lane>>4)&3)*8+e
__global__ void cast_w_kernel(const float* __restrict__ EK, const float* __restrict__ RE,
    const float* __restrict__ NW, const float* __restrict__ SK, const float* __restrict__ RS,
    f16* __restrict__ WcatT, f16* __restrict__ WsrF){
  int tid = blockIdx.x * 256 + threadIdx.x;
  if (tid < 458752){
    int n = tid >> 8, k = tid & 255;
    float v;
    if (n < 256)       v = EK[k*256 + n];
    else if (n < 1024) v = RE[k*768 + (n-256)];
    else               v = NW[k*768 + (n-1024)];
    WcatT[n*256 + k] = (f16)v;
  } else {
    int idx = tid - 458752;            // 0..262143
    int e    = idx & 7;
    int lane = (idx >> 3) & 63;
    int kt   = (idx >> 9) & 7;
    int ct   = idx >> 12;              // 0..63
    int col  = ct*16 + (lane & 15);
    int k    = kt*32 + ((lane >> 4) & 3)*8 + e;
    float v = (col < 256) ? SK[k*256 + col] : RS[k*768 + (col-256)];
    WsrF[idx] = (f16)v;
  }
}

// ---- GEMM: C[r=tsl*1024+b][0:1792) = X[b][t_start+tsl][:] @ WcatT^T (fp32 A in-reg cast) ----
__global__ __launch_bounds__(256, 2) void gemm_f16_kernel(
    const float* __restrict__ X, const f16* __restrict__ Bm,
    f16* __restrict__ C, int Mtiles, int t_start)
{
  __shared__ f16 As[128*64];
  __shared__ f16 Bs[128*64];
  const int NT = 14;
  const int nwg = Mtiles * NT;
  int bid = blockIdx.x, wg = bid;
  if ((nwg & 7) == 0){ int cpx = nwg >> 3; wg = (bid & 7) * cpx + (bid >> 3); }
  const int mt = wg / NT, nt = wg % NT;
  const int tsl = mt >> 3;
  const int b0  = (mt & 7) * 128;
  const int t   = t_start + tsl;
  const int n0  = nt * 128;
  const int tid = threadIdx.x;
  const int l = tid & 63, wid = tid >> 6;
  const int wr = wid >> 1, wc = wid & 1;
  const int srow = tid >> 3;
  const int scol = (tid & 7) * 8;

  const size_t ASTR = 32ull * 65536ull;   // 32 b-rows in fp32 elems (T*U = 65536)
  const float* Ab = X + ((size_t)(b0 + srow) * 256 + t) * 256 + scol;
  const f16*   Bb = Bm + ((size_t)(n0 + srow)) * 256 + scol;

  f16x8 ra[4], rb[4];
  #pragma unroll
  for (int j = 0; j < 4; ++j){
    f32x4 v0 = *(const f32x4*)(Ab + (size_t)j * ASTR);
    f32x4 v1 = *(const f32x4*)(Ab + (size_t)j * ASTR + 4);
    f16x8 h;
    #pragma unroll
    for (int jj = 0; jj < 8; ++jj) h[jj] = (f16)((jj < 4) ? v0[jj] : v1[jj-4]);
    ra[j] = h;
    rb[j] = *(const f16x8*)(Bb + (size_t)j * 32 * 256);
  }

  f32x4 acc[4][4];
  #pragma unroll
  for (int mi = 0; mi < 4; ++mi)
    #pragma unroll
    for (int ni = 0; ni < 4; ++ni)
      acc[mi][ni] = (f32x4){0.f,0.f,0.f,0.f};

  for (int kt = 0; kt < 4; ++kt){
    #pragma unroll
    for (int j = 0; j < 4; ++j){
      int row = srow + j*32;
      int e = (row*64 + scol) ^ ((row & 7) << 3);
      *(f16x8*)&As[e] = ra[j];
      *(f16x8*)&Bs[e] = rb[j];
    }
    __syncthreads();
    if (kt < 3){
      #pragma unroll
      for (int j = 0; j < 4; ++j){
        f32x4 v0 = *(const f32x4*)(Ab + (kt+1)*64 + (size_t)j * ASTR);
        f32x4 v1 = *(const f32x4*)(Ab + (kt+1)*64 + (size_t)j * ASTR + 4);
        f16x8 h;
        #pragma unroll
        for (int jj = 0; jj < 8; ++jj) h[jj] = (f16)((jj < 4) ? v0[jj] : v1[jj-4]);
        ra[j] = h;
        rb[j] = *(const f16x8*)(Bb + (kt+1)*64 + (size_t)j * 32 * 256);
      }
    }
    #pragma unroll
    for (int kk = 0; kk < 2; ++kk){
      f16x8 af[4], bfr[4];
      #pragma unroll
      for (int mi = 0; mi < 4; ++mi){
        int row = wr*64 + mi*16 + (l & 15);
        int e = (row*64 + kk*32 + (l >> 4)*8) ^ ((row & 7) << 3);
        af[mi] = *(const f16x8*)&As[e];
      }
      #pragma unroll
      for (int ni = 0; ni < 4; ++ni){
        int row = wc*64 + ni*16 + (l & 15);
        int e = (row*64 + kk*32 + (l >> 4)*8) ^ ((row & 7) << 3);
        bfr[ni] = *(const f16x8*)&Bs[e];
      }
      #pragma unroll
      for (int mi = 0; mi < 4; ++mi)
        #pragma unroll
        for (int ni = 0; ni < 4; ++ni)
          acc[mi][ni] = mfma16(af[mi], bfr[ni], acc[mi][ni]);
    }
    __syncthreads();
  }
  const size_t m0 = (size_t)mt * 128;
  #pragma unroll
  for (int mi = 0; mi < 4; ++mi){
    #pragma unroll
    for (int ni = 0; ni < 4; ++ni){
      int col = n0 + wc*64 + ni*16 + (l & 15);
      size_t row = m0 + wr*64 + mi*16 + ((l >> 4) * 4);
      #pragma unroll
      for (int j = 0; j < 4; ++j)
        C[(row + j) * 1792 + col] = (f16)acc[mi][ni][j];
    }
  }
}

// ---------- recurrent v8: 256 blocks x 4 rows, 512 threads (8 waves) ----------
__global__ __launch_bounds__(512, 1) void recurrent_kernel(
    const f16* __restrict__ P, const f16* __restrict__ WsrF,
    const float* __restrict__ bias, const float* __restrict__ Lk,
    float* __restrict__ state, float* __restrict__ out,
    int t0, int nsteps)
{
  __shared__ f16 Wl[8*8192];             // weights kt6..7: 128 KB
  __shared__ f16 qg16[4*1032];           // qg as f16: [row j][1032]
  __shared__ f16 stA[8*520];             // state f16, fragment-major [kt][lane][8]
  __shared__ __align__(16) float sb[256];
  __shared__ __align__(16) float sl[256];
  __shared__ float sp[4][2][3];          // score partials [row][half][slot]

  const int tid = threadIdx.x;
  const int l = tid & 63, w = tid >> 6;  // 8 waves
  const int r0 = blockIdx.x * 4;
  const int arow = l & 15, agrp = l >> 4;
  const int r = w >> 1, h = w & 1;       // row 0..3, half 0..1 (wave pair per row)
  const int c2 = h*128 + l*2;            // 2 cols/lane
  const int gb = r0 + r;
  const size_t SL = 1024ull*1792ull;
  const size_t gbo = (size_t)gb*1792;

  if (tid < 256){ sb[tid] = bias[tid]; sl[tid] = Lk[tid]; }
  for (int j = tid; j < 8*520; j += 512) stA[j] = (f16)0.f;

  // ---- persistent weights: kt0..5 -> 192 regs/wave ----
  const f16* const wbase = WsrF + (size_t)w*32768 + l*8;   // wave's 8 ct-tiles
  f16x8 Wreg[8][6];
  #pragma unroll
  for (int ct = 0; ct < 8; ++ct)
    #pragma unroll
    for (int kt = 0; kt < 6; ++kt)
      Wreg[ct][kt] = *(const f16x8*)(wbase + (ct*8 + kt)*512);
  // ---- kt6..7 -> LDS (128 KB, loaded once) ----
  #pragma unroll
  for (int ct = 0; ct < 8; ++ct)
    #pragma unroll
    for (int k2 = 0; k2 < 2; ++k2)
      *(f16x8*)&Wl[w*8192 + (ct*2 + k2)*512 + l*8] =
          *(const f16x8*)(wbase + (ct*8 + 6 + k2)*512);
  __syncthreads();

  // state: 2 cols/lane, rows 0..3 of stA valid (rest stay zero)
  f32x2 sn = *(const f32x2*)(state + (size_t)gb*256 + c2);
  const int kt0 = c2 >> 5, g0 = (c2 >> 3) & 3, e0 = c2 & 7;
  f16* const sa = &stA[kt0*520 + (g0*16 + r)*8 + e0];
  { f16x2 hh; hh[0]=(f16)sn[0]; hh[1]=(f16)sn[1]; *(f16x2*)sa = hh; }
  lgkm_barrier();

  for (int i = 0; i < nsteps; ++i){
    const int t = t0 + i;
    const f16* p2 = P + (size_t)(i+2)*SL + gbo;
    const f16* p1 = P + (size_t)(i+1)*SL + gbo;
    const f16* p0 = P + (size_t)(i+0)*SL + gbo;

    // ---- keep-alive: pin persistent weights across the step loop ----
    #pragma unroll
    for (int ct = 0; ct < 8; ++ct)
      #pragma unroll
      for (int kt = 0; kt < 6; ++kt)
        asm volatile("" : "+v"(Wreg[ct][kt]));

    // ---- scores-critical loads only, upfront (3 regs; GRU loads deferred) ----
    const f16x2 cE2 = *(const f16x2*)(p2 + c2);
    const f16x2 E0  = *(const f16x2*)(p0 + c2);
    const f16x2 E1  = *(const f16x2*)(p1 + c2);

    // ---- phase 1: two half-passes (acc[4], kt-outer, pipelined av) ----
    #pragma unroll
    for (int half = 0; half < 2; ++half){
      f32x4 acc[4];
      #pragma unroll
      for (int c = 0; c < 4; ++c) acc[c] = (f32x4){0.f,0.f,0.f,0.f};
      f16x8 av0 = *(const f16x8*)&stA[0*520 + l*8];
      f16x8 av1 = *(const f16x8*)&stA[1*520 + l*8];
      #pragma unroll
      for (int kt = 0; kt < 8; ++kt){
        const f16x8 avc = (kt & 1) ? av1 : av0;
        if (kt < 6){
          f16x8 nx = *(const f16x8*)&stA[(kt+2)*520 + l*8];
          if (kt & 1) av1 = nx; else av0 = nx;
        }
        #pragma unroll
        for (int c = 0; c < 4; ++c){
          const int ct = half*4 + c;
          f16x8 B = (kt < 6) ? Wreg[ct][kt]
                             : *(const f16x8*)&Wl[w*8192 + (ct*2 + (kt-6))*512 + l*8];
          acc[c] = mfma16(avc, B, acc[c]);
        }
      }
      // qg write: keep C rows 0..3 only (agrp==0); col = w*128 + ct*16 + arow
      if (agrp == 0){
        #pragma unroll
        for (int c = 0; c < 4; ++c){
          const int ct = half*4 + c;
          #pragma unroll
          for (int j = 0; j < 4; ++j)
            qg16[j*1032 + w*128 + ct*16 + arow] = (f16)acc[c][j];
        }
      }
    }

    // ---- deferred cold/warm GRU loads (consumed ~1.5K cycles away) ----
    const f16x2 cU  = *(const f16x2*)(p2 +  256 + c2);
    const f16x2 cR  = *(const f16x2*)(p2 +  512 + c2);
    const f16x2 cC  = *(const f16x2*)(p2 +  768 + c2);
    const f16x2 cNU = *(const f16x2*)(p2 + 1024 + c2);
    const f16x2 cNR = *(const f16x2*)(p2 + 1280 + c2);
    const f16x2 cNC = *(const f16x2*)(p2 + 1536 + c2);
    lgkm_barrier();

    const f16x2 U1 = *(const f16x2*)(p1 + 256 + c2);
    const f16x2 R1 = *(const f16x2*)(p1 + 512 + c2);
    const f16x2 C1 = *(const f16x2*)(p1 + 768 + c2);
    const f16x2 U2 = *(const f16x2*)(p0 + 256 + c2);
    const f16x2 R2 = *(const f16x2*)(p0 + 512 + c2);
    const f16x2 C2 = *(const f16x2*)(p0 + 768 + c2);

    // ---- phase 2a: score partials (row r, 128 cols per wave, 2/lane) ----
    {
      const f16x2 qv = *(const f16x2*)&qg16[r*1032 + c2];
      const f32x2 bb = *(const f32x2*)&sb[c2];
      const f32x2 lk = *(const f32x2*)&sl[c2];
      float s0 = 0.f, s1 = 0.f, s2 = 0.f;
      #pragma unroll
      for (int j = 0; j < 2; ++j){
        const float qb = (float)qv[j] + bb[j];
        s0 += tanh_f((float)E0[j]  + qb) * lk[j];
        s1 += tanh_f((float)E1[j]  + qb) * lk[j];
        s2 += tanh_f((float)cE2[j] + qb) * lk[j];
      }
      #pragma unroll
      for (int off = 32; off; off >>= 1){
        s0 += __shfl_xor(s0, off);
        s1 += __shfl_xor(s1, off);
        s2 += __shfl_xor(s2, off);
      }
      if (l == 0){ sp[r][h][0] = s0; sp[r][h][1] = s1; sp[r][h][2] = s2; }
    }
    lgkm_barrier();

    // ---- phase 2b: softmax (from partials, redundant per lane) + GRU ----
    {
      const float s0 = sp[r][0][0] + sp[r][1][0];
      const float s1 = sp[r][0][1] + sp[r][1][1];
      const float s2 = sp[r][0][2] + sp[r][1][2];
      const float mx = fmaxf(fmaxf(s0, s1), s2);
      const float x0 = __expf(s0 - mx), x1 = __expf(s1 - mx), x2 = __expf(s2 - mx);
      const float inv = 1.0f / (x0 + x1 + x2);
      const float pr0 = x0*inv, pr1 = x1*inv, pr2 = x2*inv;

      const f16x2 qu = *(const f16x2*)&qg16[r*1032 + 256 + c2];
      const f16x2 qr = *(const f16x2*)&qg16[r*1032 + 512 + c2];
      const f16x2 qc = *(const f16x2*)&qg16[r*1032 + 768 + c2];
      #pragma unroll
      for (int j = 0; j < 2; ++j){
        const float geu = pr2*(float)cU[j] + pr1*(float)U1[j] + pr0*(float)U2[j];
        const float ger = pr2*(float)cR[j] + pr1*(float)R1[j] + pr0*(float)R2[j];
        const float gec = pr2*(float)cC[j] + pr1*(float)C1[j] + pr0*(float)C2[j];
        const float up   = sigmoid_f((float)qu[j] + geu + (float)cNU[j]);
        const float rp   = sigmoid_f((float)qr[j] + ger + (float)cNR[j]);
        const float cand = tanh_f(rp*(float)qc[j] + gec + (float)cNC[j]);
        sn[j] = (1.0f - up)*sn[j] + up*cand;
      }
      { f16x2 hh; hh[0]=(f16)sn[0]; hh[1]=(f16)sn[1]; *(f16x2*)sa = hh; }
      if (t == 255) *(f32x2*)(out + (size_t)gb*256 + c2) = sn;
    }
    lgkm_barrier();
  }

  *(f32x2*)(state + (size_t)gb*256 + c2) = sn;
}

// ---------------------------------- launch ----------------------------------
extern "C" void kernel_launch(void* const* d_in, const int* in_sizes, int n_in,
                              void* d_out, int out_size, void* d_ws, size_t ws_size,
                              hipStream_t stream)
{
  const float* X  = (const float*)d_in[0];
  const float* EK = (const float*)d_in[1];
  const float* SK = (const float*)d_in[2];
  const float* BI = (const float*)d_in[3];
  const float* LK = (const float*)d_in[4];
  const float* RS = (const float*)d_in[5];
  const float* RE = (const float*)d_in[6];
  const float* NW = (const float*)d_in[7];
  float* out = (float*)d_out;
  char* ws = (char*)d_ws;

  const size_t slabB = 1024ull * 1792ull * 2ull;   // 3,670,016 B
  const size_t wB    = 917504ull + 524288ull + 1048576ull;
  int CT = 4;
  if      (ws_size >= 66ull*slabB + wB) CT = 64;
  else if (ws_size >= 34ull*slabB + wB) CT = 32;
  else if (ws_size >= 18ull*slabB + wB) CT = 16;
  else if (ws_size >= 10ull*slabB + wB) CT = 8;

  f16* P = (f16*)ws;
  size_t poff = (size_t)(CT + 2) * slabB;
  f16* WcatT = (f16*)(ws + poff);
  f16* WsrF  = (f16*)(ws + poff + 917504ull);
  float* state = (float*)(ws + poff + 917504ull + 524288ull);

  hipMemsetAsync(state, 0, 1048576ull, stream);
  hipMemsetAsync(P, 0, 2ull*slabB, stream);        // zero "virtual" slabs t=-2,-1
  cast_w_kernel<<<2816, 256, 0, stream>>>(EK, RE, NW, SK, RS, WcatT, WsrF);

  const int nch = 256 / CT;
  for (int c = 0; c < nch; ++c){
    const int t0 = c * CT;
    const int t_start  = (c == 0) ? 0 : (t0 - 2);
    const int slab_off = (c == 0) ? 2 : 0;
    const int Mtiles = (((c == 0) ? CT : (CT + 2)) * 1024) / 128;
    gemm_f16_kernel<<<Mtiles * 14, 256, 0, stream>>>(
        X, WcatT, P + (size_t)slab_off * 1024 * 1792, Mtiles, t_start);
    recurrent_kernel<<<256, 512, 0, stream>>>(P, WsrF, BI, LK, state, out, t0, CT);
  }
}